// Round 5
// baseline (659.248 us; speedup 1.0000x reference)
//
#include <hip/hip_runtime.h>

typedef unsigned short u16;
typedef unsigned int u32;
typedef __attribute__((ext_vector_type(8))) short bf16x8;
typedef __attribute__((ext_vector_type(4))) float f32x4;

#define LDK 72   // A-tile LDS stride (64 + 8 pad)

__device__ __forceinline__ u16 f2bf(float f) {
    u32 u = __float_as_uint(f);
    u += 0x7fffu + ((u >> 16) & 1u);   // round-to-nearest-even
    return (u16)(u >> 16);
}

__device__ __forceinline__ f32x4 mfma16(bf16x8 a, bf16x8 b, f32x4 c) {
    return __builtin_amdgcn_mfma_f32_16x16x32_bf16(a, b, c, 0, 0, 0);
}

// ---------------- prep: fold numeric features ----------------

__global__ __launch_bounds__(256) void prep_u_kernel(
    const float* __restrict__ w_num, const float* __restrict__ b_num,
    const float* __restrict__ W_first, float* __restrict__ U, float* __restrict__ P)
{
    __shared__ float wrow[256];
    __shared__ float brow[256];
    int j = threadIdx.x, f = blockIdx.x;
    wrow[j] = w_num[f * 256 + j];
    brow[j] = b_num[f * 256 + j];
    __syncthreads();
    float au = 0.f, ap = 0.f;
    for (int k = 0; k < 256; k++) {
        float w = W_first[(size_t)((f << 8) + k) * 256 + j];
        au = fmaf(wrow[k], w, au);
        ap = fmaf(brow[k], w, ap);
    }
    U[f * 256 + j] = au;
    P[f * 256 + j] = ap;
}

__global__ __launch_bounds__(256) void prep_c0_kernel(
    const float* __restrict__ b_first, const float* __restrict__ P, float* __restrict__ c0)
{
    int j = threadIdx.x;
    float a = b_first[j];
    for (int f = 0; f < 32; f++) a += P[f * 256 + j];
    c0[j] = a;
}

// ---------------- prep: LDS-tiled transpose f32 -> bf16 ----------------
// out[c0+c][k_off + r0 + r] = (r0+r < R) ? in[(r0+r)*C + c0+c] : 0
// grid: (Rpad/64, C/64, batches); block 256. Coalesced reads AND writes.
__global__ __launch_bounds__(256) void transpose_kernel(
    const float* __restrict__ in, u16* __restrict__ out,
    int R, int C, int ldo, int k_off, size_t in_stride, size_t out_stride)
{
    __shared__ float t[64][65];
    in  += (size_t)blockIdx.z * in_stride;
    out += (size_t)blockIdx.z * out_stride;
    const int tid = threadIdx.x;
    const int r0 = blockIdx.x * 64, c0 = blockIdx.y * 64;
#pragma unroll
    for (int i = 0; i < 16; i++) {
        int e = tid + i * 256;            // 0..4095
        int r = e >> 6, c = e & 63;       // 64 consecutive lanes -> consecutive c
        float v = (r0 + r < R) ? in[(size_t)(r0 + r) * C + c0 + c] : 0.f;
        t[c][r] = v;                      // bank = (c + r) % 32 -> 2-way, free
    }
    __syncthreads();
#pragma unroll
    for (int i = 0; i < 2; i++) {
        int e = tid + i * 256;            // 0..511
        int c = e >> 3, r8 = (e & 7) * 8;
        u16 tmp[8];
#pragma unroll
        for (int x = 0; x < 8; x++) tmp[x] = f2bf(t[c][r8 + x]);
        *(bf16x8*)&out[(size_t)(c0 + c) * ldo + k_off + r0 + r8] = *(bf16x8*)tmp;
    }
}

// ---------------- first layer: gathered-A GEMM, BM=32 x full N=256 ----------------
// Bb staged via global_load_lds (16B DMA) into an XOR-swizzled no-pad layout:
//   logical (n-row r, 8-elem group c8) lives at phys slot (r, c8 ^ (r&7)).
#define FBM 32

#define GATHER(KQ, G0, G1)                                                    \
    {                                                                         \
        int chunk = tid;                                                      \
        int r = chunk >> 4, c4 = chunk & 15;                                  \
        int k = (KQ) + c4 * 4;                                                \
        if (k < 4096) {                                                       \
            int rowi = sidx[r * 16 + (k >> 8)];                               \
            G0 = *(const float4*)&cemb[(size_t)rowi * 256 + (k & 255)];       \
        } else if (k < 4128) {                                                \
            int c = k - 4096;                                                 \
            G0.x = sx[r * 32 + c];     G0.y = sx[r * 32 + c + 1];             \
            G0.z = sx[r * 32 + c + 2]; G0.w = sx[r * 32 + c + 3];             \
        } else G0 = make_float4(0.f, 0.f, 0.f, 0.f);                          \
        chunk = tid + 256;                                                    \
        r = chunk >> 4; c4 = chunk & 15;                                      \
        k = (KQ) + c4 * 4;                                                    \
        if (k < 4096) {                                                       \
            int rowi = sidx[r * 16 + (k >> 8)];                               \
            G1 = *(const float4*)&cemb[(size_t)rowi * 256 + (k & 255)];       \
        } else if (k < 4128) {                                                \
            int c = k - 4096;                                                 \
            G1.x = sx[r * 32 + c];     G1.y = sx[r * 32 + c + 1];             \
            G1.z = sx[r * 32 + c + 2]; G1.w = sx[r * 32 + c + 3];             \
        } else G1 = make_float4(0.f, 0.f, 0.f, 0.f);                          \
    }

__global__ __launch_bounds__(256) void first_gemm_kernel(
    const u16* __restrict__ BT, const float* __restrict__ bias,
    float* __restrict__ outF,
    const int* __restrict__ cidx, const float* __restrict__ cemb,
    const float* __restrict__ xnum)
{
    __shared__ __align__(16) u16 Ab[FBM * LDK];    //  4608 B, padded
    __shared__ __align__(16) u16 Bb[256 * 64];     // 32768 B, swizzled no-pad
    __shared__ int   sidx[FBM * 16];
    __shared__ float sx[FBM * 32];

    const int tid = threadIdx.x;
    const int lane = tid & 63;
    const int wv = tid >> 6;
    const int quad = lane >> 4;
    const int l16 = lane & 15;
    const int m0 = blockIdx.x * FBM;

#pragma unroll
    for (int i = 0; i < 2; i++) sidx[tid + i * 256] = cidx[m0 * 16 + tid + i * 256];
    {
        float4 v = *(const float4*)&xnum[(size_t)m0 * 32 + tid * 4];
        sx[tid * 4 + 0] = v.x; sx[tid * 4 + 1] = v.y;
        sx[tid * 4 + 2] = v.z; sx[tid * 4 + 3] = v.w;
    }
    __syncthreads();

    f32x4 acc[2][4];
#pragma unroll
    for (int i = 0; i < 2; i++)
#pragma unroll
        for (int j = 0; j < 4; j++) acc[i][j] = (f32x4){0.f, 0.f, 0.f, 0.f};

    float4 ga0, ga1;
    GATHER(0, ga0, ga1);

    for (int k0 = 0; k0 < 4160; k0 += 64) {
        // ---- write prefetched A regs -> Ab (bf16) ----
        {
            int r = tid >> 4, c4 = tid & 15;
            u16* dst = &Ab[r * LDK + c4 * 4];
            dst[0] = f2bf(ga0.x); dst[1] = f2bf(ga0.y);
            dst[2] = f2bf(ga0.z); dst[3] = f2bf(ga0.w);
            int chunk = tid + 256;
            r = chunk >> 4; c4 = chunk & 15;
            dst = &Ab[r * LDK + c4 * 4];
            dst[0] = f2bf(ga1.x); dst[1] = f2bf(ga1.y);
            dst[2] = f2bf(ga1.z); dst[3] = f2bf(ga1.w);
        }
        // ---- stage Bb: async DMA, swizzled ----
#pragma unroll
        for (int it = 0; it < 8; it++) {
            int chunk = it * 256 + tid;
            int r = chunk >> 3;
            int c8 = (chunk & 7) ^ (r & 7);
            const u16* src = &BT[(size_t)r * 4160 + k0 + c8 * 8];
#if __has_builtin(__builtin_amdgcn_global_load_lds)
            __builtin_amdgcn_global_load_lds(
                (const __attribute__((address_space(1))) void*)src,
                (__attribute__((address_space(3))) void*)&Bb[(it * 256 + wv * 64) * 8],
                16, 0, 0);
#else
            *(bf16x8*)&Bb[(size_t)chunk * 8] = *(const bf16x8*)src;
#endif
        }
        // ---- prefetch next A tile (overlaps DMA drain) ----
        if (k0 + 64 < 4160) GATHER(k0 + 64, ga0, ga1);
        __syncthreads();

#pragma unroll
        for (int kk = 0; kk < 64; kk += 32) {
            bf16x8 af[2], bfr[4];
#pragma unroll
            for (int i = 0; i < 2; i++)
                af[i] = *(const bf16x8*)&Ab[(i * 16 + l16) * LDK + kk + quad * 8];
#pragma unroll
            for (int j = 0; j < 4; j++) {
                int row = wv * 64 + j * 16 + l16;
                int c8L = quad + (kk >> 3);
                bfr[j] = *(const bf16x8*)&Bb[row * 64 + ((c8L ^ (row & 7)) * 8)];
            }
#pragma unroll
            for (int i = 0; i < 2; i++)
#pragma unroll
                for (int j = 0; j < 4; j++)
                    acc[i][j] = mfma16(af[i], bfr[j], acc[i][j]);
        }
        __syncthreads();
    }

    // C/D layout: col = lane&15, row = (lane>>4)*4 + reg
#pragma unroll
    for (int i = 0; i < 2; i++) {
#pragma unroll
        for (int j = 0; j < 4; j++) {
            int col = wv * 64 + j * 16 + l16;
            float bs = bias[col];
#pragma unroll
            for (int r = 0; r < 4; r++) {
                int row = m0 + i * 16 + quad * 4 + r;
                outF[(size_t)row * 256 + col] = acc[i][j][r] + bs;
            }
        }
    }
}

// ---------------- fused residual layer, h register-resident ----------------
// One dispatch per layer (weights stay L2-hot). Block owns 32 rows; h loaded
// once in MFMA C-layout, LN stats via shfl+LDS, weights double-buffered in regs.
__global__ __launch_bounds__(256, 2) void layer_kernel(
    float* __restrict__ h,
    const float* __restrict__ g, const float* __restrict__ bta,
    const u16* __restrict__ W1, const float* __restrict__ b1,
    const u16* __restrict__ W2, const float* __restrict__ b2)
{
    __shared__ __align__(16) u16 hn[32 * 264];    // 16896 B
    __shared__ __align__(16) u16 hid[32 * 520];   // 33280 B
    __shared__ float red[256];                    //  1024 B
    const int tid  = threadIdx.x;
    const int lane = tid & 63;
    const int wv   = tid >> 6;
    const int quad = lane >> 4;
    const int l16  = lane & 15;
    const int m0   = blockIdx.x * 32;

    // ---- load h in C-layout: row = i*16+quad*4+r, col = wv*64+j*16+l16 ----
    f32x4 h_acc[2][4];
#pragma unroll
    for (int i = 0; i < 2; i++)
#pragma unroll
        for (int j = 0; j < 4; j++) {
            int col = wv * 64 + j * 16 + l16;
#pragma unroll
            for (int r = 0; r < 4; r++)
                h_acc[i][j][r] = h[(size_t)(m0 + i * 16 + quad * 4 + r) * 256 + col];
        }

    // ---- LN stats ----
#pragma unroll
    for (int i = 0; i < 2; i++)
#pragma unroll
        for (int r = 0; r < 4; r++) {
            float a = h_acc[i][0][r] + h_acc[i][1][r] + h_acc[i][2][r] + h_acc[i][3][r];
            float b = h_acc[i][0][r] * h_acc[i][0][r] + h_acc[i][1][r] * h_acc[i][1][r]
                    + h_acc[i][2][r] * h_acc[i][2][r] + h_acc[i][3][r] * h_acc[i][3][r];
#pragma unroll
            for (int o = 1; o < 16; o <<= 1) { a += __shfl_xor(a, o); b += __shfl_xor(b, o); }
            if (l16 == 0) {
                int row = i * 16 + quad * 4 + r;
                red[row * 4 + wv] = a;
                red[128 + row * 4 + wv] = b;
            }
        }
    __syncthreads();
    float mu[2][4], rs[2][4];
#pragma unroll
    for (int i = 0; i < 2; i++)
#pragma unroll
        for (int r = 0; r < 4; r++) {
            int row = i * 16 + quad * 4 + r;
            float4 sv = *(const float4*)&red[row * 4];
            float4 qv = *(const float4*)&red[128 + row * 4];
            float st = sv.x + sv.y + sv.z + sv.w;
            float qt = qv.x + qv.y + qv.z + qv.w;
            float m = st * (1.f / 256.f);
            mu[i][r] = m;
            rs[i][r] = rsqrtf(qt * (1.f / 256.f) - m * m + 1e-5f);
        }
    // ---- normalize -> hn (bf16, A-operand layout) ----
    {
        float gv[4], bv[4];
#pragma unroll
        for (int j = 0; j < 4; j++) {
            int col = wv * 64 + j * 16 + l16;
            gv[j] = g[col];
            bv[j] = bta[col];
        }
#pragma unroll
        for (int i = 0; i < 2; i++)
#pragma unroll
            for (int j = 0; j < 4; j++)
#pragma unroll
                for (int r = 0; r < 4; r++) {
                    int row = i * 16 + quad * 4 + r;
                    float v = (h_acc[i][j][r] - mu[i][r]) * rs[i][r] * gv[j] + bv[j];
                    hn[row * 264 + wv * 64 + j * 16 + l16] = f2bf(v);
                }
    }
    __syncthreads();

    // ---- FC1: wave owns 128 of 512 cols; weight frags double-buffered ----
    float b1v[8];
#pragma unroll
    for (int j = 0; j < 8; j++) b1v[j] = b1[wv * 128 + j * 16 + l16];
    f32x4 acc1[2][8];
#pragma unroll
    for (int i = 0; i < 2; i++)
#pragma unroll
        for (int j = 0; j < 8; j++) acc1[i][j] = (f32x4){0.f, 0.f, 0.f, 0.f};
    {
        bf16x8 bwA[8], bwB[8];
#pragma unroll
        for (int j = 0; j < 8; j++)
            bwA[j] = *(const bf16x8*)&W1[(size_t)(wv * 128 + j * 16 + l16) * 256 + quad * 8];
#pragma unroll
        for (int kk = 0; kk < 256; kk += 32) {
            bf16x8* cur = ((kk >> 5) & 1) ? bwB : bwA;
            bf16x8* nxt = ((kk >> 5) & 1) ? bwA : bwB;
            if (kk + 32 < 256) {
#pragma unroll
                for (int j = 0; j < 8; j++)
                    nxt[j] = *(const bf16x8*)&W1[(size_t)(wv * 128 + j * 16 + l16) * 256 + kk + 32 + quad * 8];
            }
            bf16x8 af0 = *(const bf16x8*)&hn[l16 * 264 + kk + quad * 8];
            bf16x8 af1 = *(const bf16x8*)&hn[(16 + l16) * 264 + kk + quad * 8];
#pragma unroll
            for (int j = 0; j < 8; j++) {
                acc1[0][j] = mfma16(af0, cur[j], acc1[0][j]);
                acc1[1][j] = mfma16(af1, cur[j], acc1[1][j]);
            }
        }
    }
#pragma unroll
    for (int i = 0; i < 2; i++)
#pragma unroll
        for (int j = 0; j < 8; j++)
#pragma unroll
            for (int r = 0; r < 4; r++) {
                float v = acc1[i][j][r] + b1v[j];
                v = v > 0.f ? v : 0.f;
                hid[(i * 16 + quad * 4 + r) * 520 + wv * 128 + j * 16 + l16] = f2bf(v);
            }
    __syncthreads();

    // ---- FC2: wave owns 64 of 256 cols; + bias + residual; store h ----
    float b2v[4];
#pragma unroll
    for (int j = 0; j < 4; j++) b2v[j] = b2[wv * 64 + j * 16 + l16];
    f32x4 acc2[2][4];
#pragma unroll
    for (int i = 0; i < 2; i++)
#pragma unroll
        for (int j = 0; j < 4; j++) acc2[i][j] = (f32x4){0.f, 0.f, 0.f, 0.f};
    {
        bf16x8 bwA[4], bwB[4];
#pragma unroll
        for (int j = 0; j < 4; j++)
            bwA[j] = *(const bf16x8*)&W2[(size_t)(wv * 64 + j * 16 + l16) * 512 + quad * 8];
#pragma unroll
        for (int kk = 0; kk < 512; kk += 32) {
            bf16x8* cur = ((kk >> 5) & 1) ? bwB : bwA;
            bf16x8* nxt = ((kk >> 5) & 1) ? bwA : bwB;
            if (kk + 32 < 512) {
#pragma unroll
                for (int j = 0; j < 4; j++)
                    nxt[j] = *(const bf16x8*)&W2[(size_t)(wv * 64 + j * 16 + l16) * 512 + kk + 32 + quad * 8];
            }
            bf16x8 af0 = *(const bf16x8*)&hid[l16 * 520 + kk + quad * 8];
            bf16x8 af1 = *(const bf16x8*)&hid[(16 + l16) * 520 + kk + quad * 8];
#pragma unroll
            for (int j = 0; j < 4; j++) {
                acc2[0][j] = mfma16(af0, cur[j], acc2[0][j]);
                acc2[1][j] = mfma16(af1, cur[j], acc2[1][j]);
            }
        }
    }
#pragma unroll
    for (int i = 0; i < 2; i++)
#pragma unroll
        for (int j = 0; j < 4; j++) {
            int col = wv * 64 + j * 16 + l16;
#pragma unroll
            for (int r = 0; r < 4; r++) {
                int row = m0 + i * 16 + quad * 4 + r;
                h[(size_t)row * 256 + col] = h_acc[i][j][r] + acc2[i][j][r] + b2v[j];
            }
        }
}

// ---------------- head: final LN + [256 x 2] matvec ----------------
__global__ __launch_bounds__(256) void head_kernel(
    const float* __restrict__ h, const float* __restrict__ g,
    const float* __restrict__ bta, const float* __restrict__ Wh,
    const float* __restrict__ bh, float* __restrict__ out)
{
    int lane = threadIdx.x & 63;
    int row = blockIdx.x * 4 + (threadIdx.x >> 6);
    const float4 x = *(const float4*)&h[(size_t)row * 256 + lane * 4];
    float s = x.x + x.y + x.z + x.w;
    float s2 = x.x * x.x + x.y * x.y + x.z * x.z + x.w * x.w;
    for (int o = 32; o > 0; o >>= 1) { s += __shfl_xor(s, o); s2 += __shfl_xor(s2, o); }
    float mu = s * (1.f / 256.f);
    float rs = rsqrtf(s2 * (1.f / 256.f) - mu * mu + 1e-5f);
    float4 gv = *(const float4*)&g[lane * 4];
    float4 bv = *(const float4*)&bta[lane * 4];
    float xn0 = (x.x - mu) * rs * gv.x + bv.x;
    float xn1 = (x.y - mu) * rs * gv.y + bv.y;
    float xn2 = (x.z - mu) * rs * gv.z + bv.z;
    float xn3 = (x.w - mu) * rs * gv.w + bv.w;
    float4 wa = *(const float4*)&Wh[lane * 8];
    float4 wb = *(const float4*)&Wh[lane * 8 + 4];
    float d0 = xn0 * wa.x + xn1 * wa.z + xn2 * wb.x + xn3 * wb.z;
    float d1 = xn0 * wa.y + xn1 * wa.w + xn2 * wb.y + xn3 * wb.w;
    for (int o = 32; o > 0; o >>= 1) { d0 += __shfl_xor(d0, o); d1 += __shfl_xor(d1, o); }
    if (lane == 0) {
        out[(size_t)row * 2 + 0] = d0 + bh[0];
        out[(size_t)row * 2 + 1] = d1 + bh[1];
    }
}

// ---------------- launch ----------------
extern "C" void kernel_launch(void* const* d_in, const int* in_sizes, int n_in,
                              void* d_out, int out_size, void* d_ws, size_t ws_size,
                              hipStream_t stream)
{
    const float* x_num   = (const float*)d_in[0];
    const int*   cidx    = (const int*)d_in[1];
    const float* w_num   = (const float*)d_in[2];
    const float* b_num   = (const float*)d_in[3];
    const float* cemb    = (const float*)d_in[4];
    const float* W_first = (const float*)d_in[5];
    const float* b_first = (const float*)d_in[6];
    const float* ln_g    = (const float*)d_in[7];
    const float* ln_b    = (const float*)d_in[8];
    const float* W1s     = (const float*)d_in[9];
    const float* b1s     = (const float*)d_in[10];
    const float* W2s     = (const float*)d_in[11];
    const float* b2s     = (const float*)d_in[12];
    const float* g_f     = (const float*)d_in[13];
    const float* beta_f  = (const float*)d_in[14];
    const float* W_head  = (const float*)d_in[15];
    const float* b_head  = (const float*)d_in[16];
    float* out = (float*)d_out;

    char* ws = (char*)d_ws;
    float* U   = (float*)(ws + 0);          //  32 KB
    float* c0  = (float*)(ws + 32768);      //   1 KB
    float* P   = (float*)(ws + 33792);      //  32 KB
    u16* WcT   = (u16*)(ws + 66560);        // 256 x 4160 bf16
    u16* W1T   = (u16*)(ws + 2196480);      // 8 x 512 x 256 bf16
    u16* W2T   = (u16*)(ws + 4293632);      // 8 x 256 x 512 bf16
    float* h   = (float*)(ws + 6390784);    // 16384 x 256 f32
    // total ~22.4 MB

    prep_u_kernel<<<32, 256, 0, stream>>>(w_num, b_num, W_first, U, P);
    prep_c0_kernel<<<1, 256, 0, stream>>>(b_first, P, c0);
    // WcT: cat part [4096 k-rows], then U part (zero-padded to 64)
    transpose_kernel<<<dim3(64, 4, 1), 256, 0, stream>>>(
        W_first + (size_t)8192 * 256, WcT, 4096, 256, 4160, 0, 0, 0);
    transpose_kernel<<<dim3(1, 4, 1), 256, 0, stream>>>(
        U, WcT, 32, 256, 4160, 4096, 0, 0);
    transpose_kernel<<<dim3(4, 8, 8), 256, 0, stream>>>(
        W1s, W1T, 256, 512, 256, 0, 131072, 131072);
    transpose_kernel<<<dim3(8, 4, 8), 256, 0, stream>>>(
        W2s, W2T, 512, 256, 512, 0, 131072, 131072);

    first_gemm_kernel<<<512, 256, 0, stream>>>(
        WcT, c0, h, cidx, cemb, x_num);

    for (int l = 0; l < 8; l++) {
        layer_kernel<<<512, 256, 0, stream>>>(
            h, ln_g + l * 256, ln_b + l * 256,
            W1T + (size_t)l * 131072, b1s + l * 512,
            W2T + (size_t)l * 131072, b2s + l * 256);
    }
    head_kernel<<<4096, 256, 0, stream>>>(h, g_f, beta_f, W_head, b_head, out);
}